// Round 2
// baseline (220.793 us; speedup 1.0000x reference)
//
#include <hip/hip_runtime.h>
#include <hip/hip_bf16.h>

// MetaConv2d fused hypernetwork + dynamic conv, bf16 MFMA.
// out[bn,t,o] = sum_{c,k} x[bn,t+k,c] * w[bn,o,c,k] + bias[bn,o]
//   w[bn,p]   = meta[bn,:]·w_lin_w[p,:] + w_lin_b[p],  p = o*192 + c*3 + k
//   bias[bn,o]= meta[bn,:]·b_lin_w[o,:] + b_lin_b[o]
//
// Round-2 structure: block = 16 nodes, 1024 threads (16 waves), grid 512.
//  - 1 node per wave -> acc = 64 f32 (AGPR), targeting V+A <= 128 -> 4 waves/SIMD.
//  - pre-pass converts w_lin_w to bf16 into d_ws (fallback template reads f32).
//  - hyper phase: 6 tiles/wave, fully unrolled, 16B bf16 loads (prefetchable).
//  - 8 phases = 4 c-chunks x 2 o-halves; conv MFMA 16x16x32 from LDS w + global x.

#define BN_TOT   8192
#define S_LEN    64
#define C_IN     64
#define C_OUT    64
#define M_DIM    32
#define S_OUT    62

#define NT       16          // nodes per block
#define NTHREADS 1024        // 16 waves
#define OH       32          // couts per phase
#define JC       56          // j-stride per cout in LDS (48 real + 8 zeros)
#define NODE_STR 1800        // shorts per node (32*56 + 8 pad; 3600B)
#define WSH_N    (NT * NODE_STR)   // 28800 shorts = 57.6 KB
#define WLW_ROWS (C_IN * C_OUT * 3)   // 12288

typedef __attribute__((ext_vector_type(8))) short bf16x8;
typedef __attribute__((ext_vector_type(4))) float f32x4;

static __device__ __forceinline__ short f2bf(float f) {
    return __bfloat16_as_short(__float2bfloat16(f));
}

static __device__ __forceinline__ bf16x8 cvt8(float4 a, float4 b) {
    bf16x8 r;
    r[0] = f2bf(a.x); r[1] = f2bf(a.y); r[2] = f2bf(a.z); r[3] = f2bf(a.w);
    r[4] = f2bf(b.x); r[5] = f2bf(b.y); r[6] = f2bf(b.z); r[7] = f2bf(b.w);
    return r;
}

// ---------------- pre-pass: w_lin_w f32 -> bf16 in workspace ----------------
extern "C" __global__ void wlw_to_bf16(const float* __restrict__ src,
                                       short* __restrict__ dst) {
    const int i = (blockIdx.x * 256 + threadIdx.x) * 8;   // 192*256*8 == 12288*32
    const float4 a = *reinterpret_cast<const float4*>(src + i);
    const float4 b = *reinterpret_cast<const float4*>(src + i + 4);
    *reinterpret_cast<bf16x8*>(dst + i) = cvt8(a, b);
}

// ---------------- fused kernel (templated on workspace availability) --------
template <int USE_WS>
__global__ void __launch_bounds__(NTHREADS, 4)
metaconv_fused(const float* __restrict__ meta,   // [8192][32]
               const float* __restrict__ x,      // [8192][64][64]
               const float* __restrict__ wlw,    // [12288][32] f32
               const short* __restrict__ wlwbf,  // [12288][32] bf16 (d_ws)
               const float* __restrict__ wlb,    // [12288]
               const float* __restrict__ blw,    // [64][32]
               const float* __restrict__ blb,    // [64]
               float* __restrict__ out)          // [8192][62][64]
{
    __shared__ short wsh[WSH_N];
    __shared__ float bias_s[NT][C_OUT];

    const int tid  = threadIdx.x;
    const int wave = tid >> 6;      // 0..15 == node index within block
    const int lane = tid & 63;
    const int l16  = lane & 15;
    const int g    = lane >> 4;
    const int bn0  = blockIdx.x * NT;

    // zero LDS once: provides the zero pad at j 48..55 read by the 2nd K-step
    for (int i = tid; i < WSH_N; i += NTHREADS) wsh[i] = 0;

    // per-block bias table: exactly one (node,o) per thread (16*64 == 1024)
    {
        const int node = tid >> 6;
        const int o    = tid & 63;
        const float* mrow = meta + (size_t)(bn0 + node) * M_DIM;
        const float* brow = blw + o * M_DIM;
        float s = blb[o];
        #pragma unroll
        for (int m = 0; m < M_DIM; ++m) s += mrow[m] * brow[m];
        bias_s[node][o] = s;
    }

    // meta B-fragment (N=16 nodes, K=32): reused by every hyper MFMA
    bf16x8 metaF;
    {
        const float* mp = meta + (size_t)(bn0 + l16) * M_DIM + g * 8;
        metaF = cvt8(*reinterpret_cast<const float4*>(mp),
                     *reinterpret_cast<const float4*>(mp + 4));
    }

    const f32x4 ZV = {0.f, 0.f, 0.f, 0.f};
    f32x4 acc[4][4];                 // [t-tile][o-tile], 64 f32
    #pragma unroll
    for (int t = 0; t < 4; ++t)
        #pragma unroll
        for (int o = 0; o < 4; ++o) acc[t][o] = ZV;

    __syncthreads();

    #pragma unroll 1
    for (int cchunk = 0; cchunk < 4; ++cchunk) {
        const int c0 = cchunk * 16;
        #pragma unroll
        for (int ohalf = 0; ohalf < 2; ++ohalf) {
            const int obase = ohalf * OH;
            const int o_l0  = wave * 2;

            // ---------------- hypernetwork phase ----------------
            // 96 row-tiles = (o_l 0..31) x (k 0..2); 6 per wave, fully unrolled.
            #pragma unroll
            for (int i = 0; i < 6; ++i) {
                const int o_l  = o_l0 + (i >= 3 ? 1 : 0);
                const int k    = (i >= 3) ? (i - 3) : i;
                const int orow = obase + o_l;
                const int p    = orow * 192 + (c0 + l16) * 3 + k;
                bf16x8 aF;
                if constexpr (USE_WS) {
                    aF = *reinterpret_cast<const bf16x8*>(wlwbf + (size_t)p * M_DIM + g * 8);
                } else {
                    const float* wp = wlw + (size_t)p * M_DIM + g * 8;
                    aF = cvt8(*reinterpret_cast<const float4*>(wp),
                              *reinterpret_cast<const float4*>(wp + 4));
                }
                f32x4 d = __builtin_amdgcn_mfma_f32_16x16x32_bf16(aF, metaF, ZV, 0, 0, 0);
                // lane holds rows cc = g*4+r for node = l16; add w_lin_b, store bf16
                const int ccb = g * 4;
                const int pb  = orow * 192 + k;
                const short r0 = f2bf(d[0] + wlb[pb + (c0 + ccb + 0) * 3]);
                const short r1 = f2bf(d[1] + wlb[pb + (c0 + ccb + 1) * 3]);
                const short r2 = f2bf(d[2] + wlb[pb + (c0 + ccb + 2) * 3]);
                const short r3 = f2bf(d[3] + wlb[pb + (c0 + ccb + 3) * 3]);
                const int off = l16 * NODE_STR + o_l * JC + k * 16 + ccb;
                *reinterpret_cast<short4*>(&wsh[off]) = make_short4(r0, r1, r2, r3);
            }
            __syncthreads();

            // ---------------- conv phase (wave owns node == wave) ----------------
            const float* xb    = x + (size_t)(bn0 + wave) * (S_LEN * C_IN);
            const short* wnode = &wsh[wave * NODE_STR];
            #pragma unroll
            for (int tt = 0; tt < 4; ++tt) {
                const int t0 = tt * 16;
                // A0: elem e of group g -> j=g*8+e: k=g>>1, c=c0+(g&1)*8+e (row t0+l16)
                int row0 = t0 + l16 + (g >> 1);
                row0 = row0 < 63 ? row0 : 63;              // t>=62 rows discarded
                const float* xp = xb + row0 * C_IN + c0 + (g & 1) * 8;
                const bf16x8 A0 = cvt8(*reinterpret_cast<const float4*>(xp),
                                       *reinterpret_cast<const float4*>(xp + 4));
                // A1: kk=g*8+e<16 -> j=32+kk: k=2, c=c0+kk; kk>=16 contributes 0
                bf16x8 A1;
                if (g < 2) {
                    int row1 = t0 + l16 + 2;
                    row1 = row1 < 63 ? row1 : 63;
                    const float* xq = xb + row1 * C_IN + c0 + g * 8;
                    A1 = cvt8(*reinterpret_cast<const float4*>(xq),
                              *reinterpret_cast<const float4*>(xq + 4));
                } else {
                    A1[0]=0; A1[1]=0; A1[2]=0; A1[3]=0;
                    A1[4]=0; A1[5]=0; A1[6]=0; A1[7]=0;
                }
                #pragma unroll
                for (int ol = 0; ol < 2; ++ol) {
                    const short* wrow = wnode + (ol * 16 + l16) * JC;
                    const bf16x8 B0 = *reinterpret_cast<const bf16x8*>(&wrow[g * 8]);
                    const bf16x8 B1 = *reinterpret_cast<const bf16x8*>(&wrow[32 + g * 8]);
                    acc[tt][ohalf * 2 + ol] =
                        __builtin_amdgcn_mfma_f32_16x16x32_bf16(A0, B0, acc[tt][ohalf * 2 + ol], 0, 0, 0);
                    acc[tt][ohalf * 2 + ol] =
                        __builtin_amdgcn_mfma_f32_16x16x32_bf16(A1, B1, acc[tt][ohalf * 2 + ol], 0, 0, 0);
                }
            }
            __syncthreads();
        }
    }

    // ---------------- epilogue: add bias, store f32 ----------------
    float* ob = out + (size_t)(bn0 + wave) * (S_OUT * C_OUT);
    #pragma unroll
    for (int tt = 0; tt < 4; ++tt) {
        #pragma unroll
        for (int ot = 0; ot < 4; ++ot) {
            const int o  = ot * 16 + l16;
            const float bv = bias_s[wave][o];
            #pragma unroll
            for (int r = 0; r < 4; ++r) {
                const int t = tt * 16 + g * 4 + r;   // D: row = g*4+r, col = l16
                if (t < S_OUT) ob[t * C_OUT + o] = acc[tt][ot][r] + bv;
            }
        }
    }
}

extern "C" void kernel_launch(void* const* d_in, const int* in_sizes, int n_in,
                              void* d_out, int out_size, void* d_ws, size_t ws_size,
                              hipStream_t stream) {
    const float* meta = (const float*)d_in[0];
    const float* x    = (const float*)d_in[1];
    const float* wlw  = (const float*)d_in[2];
    const float* wlb  = (const float*)d_in[3];
    const float* blw  = (const float*)d_in[4];
    const float* blb  = (const float*)d_in[5];
    float* out = (float*)d_out;
    (void)in_sizes; (void)n_in; (void)out_size;

    const size_t wlw_bytes = (size_t)WLW_ROWS * M_DIM * sizeof(short);  // 786432
    short* wlwbf = (short*)d_ws;

    if (ws_size >= wlw_bytes) {
        wlw_to_bf16<<<dim3(WLW_ROWS * M_DIM / (256 * 8)), dim3(256), 0, stream>>>(wlw, wlwbf);
        metaconv_fused<1><<<dim3(BN_TOT / NT), dim3(NTHREADS), 0, stream>>>(
            meta, x, wlw, wlwbf, wlb, blw, blb, out);
    } else {
        metaconv_fused<0><<<dim3(BN_TOT / NT), dim3(NTHREADS), 0, stream>>>(
            meta, x, wlw, wlwbf, wlb, blw, blb, out);
    }
}

// Round 3
// 178.320 us; speedup vs baseline: 1.2382x; 1.2382x over previous
//
#include <hip/hip_runtime.h>
#include <hip/hip_bf16.h>

// MetaConv2d fused hypernetwork + dynamic conv, bf16 MFMA. Round 3.
// out[bn,t,o] = sum_{c,k} x[bn,t+k,c] * w[bn,o,c,k] + bias[bn,o]
//   w[bn,p]   = meta[bn,:]·w_lin_w[p,:] + w_lin_b[p],  p = o*192 + c*3 + k
//
// Block = 8 nodes, 1024 threads (16 waves = 8 nodes x 2 t-halves), grid 1024.
//  - acc = 32 f32/lane (AGPR) -> 96 arch VGPR budget at 4 waves/SIMD: no spills.
//  - contraction j = k*32 + cc: 6 full K=32 conv MFMAs/phase, no zero padding.
//  - w_lin_b folded into hyper MFMA C operand.
//  - 8 phases (2 c-chunks x 4 o-quarters), LDS double-buffered, 1 barrier/phase:
//    hyper(p+1) -> buf[(p+1)&1] overlaps conv(p) <- buf[p&1].

#define BN_TOT   8192
#define C_IN     64
#define C_OUT    64
#define M_DIM    32
#define S_OUT    62

#define NT       8            // nodes per block
#define NTHREADS 1024         // 16 waves
#define OSTR     104          // shorts per o: 3k*32cc + 8 pad (16B-aligned, 2-way banks)
#define NODESTR  1672         // 16*OSTR + 8
#define HALF     (NT * NODESTR)   // 13376 shorts = 26752 B per buffer
#define WLW_ROWS 12288

typedef __attribute__((ext_vector_type(8))) short bf16x8;
typedef __attribute__((ext_vector_type(4))) float f32x4;

static __device__ __forceinline__ short f2bf(float f) {
    return __bfloat16_as_short(__float2bfloat16(f));
}

static __device__ __forceinline__ bf16x8 cvt8(float4 a, float4 b) {
    bf16x8 r;
    r[0] = f2bf(a.x); r[1] = f2bf(a.y); r[2] = f2bf(a.z); r[3] = f2bf(a.w);
    r[4] = f2bf(b.x); r[5] = f2bf(b.y); r[6] = f2bf(b.z); r[7] = f2bf(b.w);
    return r;
}

// ---------------- pre-pass: w_lin_w f32 -> bf16 in workspace ----------------
extern "C" __global__ void wlw_to_bf16(const float* __restrict__ src,
                                       short* __restrict__ dst) {
    const int i = (blockIdx.x * 256 + threadIdx.x) * 8;   // 192 blocks cover 12288*32
    const float4 a = *reinterpret_cast<const float4*>(src + i);
    const float4 b = *reinterpret_cast<const float4*>(src + i + 4);
    *reinterpret_cast<bf16x8*>(dst + i) = cvt8(a, b);
}

// ---------------- fused kernel ----------------
template <int USE_WS>
__global__ void __launch_bounds__(NTHREADS, 4)
metaconv_fused(const float* __restrict__ meta,   // [8192][32]
               const float* __restrict__ x,      // [8192][64][64]
               const float* __restrict__ wlw,    // [12288][32] f32
               const short* __restrict__ wlwbf,  // [12288][32] bf16 (d_ws)
               const float* __restrict__ wlb,    // [12288]
               const float* __restrict__ blw,    // [64][32]
               const float* __restrict__ blb,    // [64]
               float* __restrict__ out)          // [8192][62][64]
{
    __shared__ short wsh[2 * HALF];              // double-buffered w tiles
    __shared__ float bias_s[NT][C_OUT];

    const int tid   = threadIdx.x;
    const int wave  = tid >> 6;                  // 0..15
    const int lane  = tid & 63;
    const int l16   = lane & 15;
    const int g     = lane >> 4;
    const int node  = wave & (NT - 1);           // conv: wave's node
    const int thalf = wave >> 3;                 // conv: wave's t-half
    const int bn0   = blockIdx.x * NT;

    // per-block bias table: one (node,o) per thread for tid < 512
    if (tid < NT * C_OUT) {
        const int bnode = tid >> 6;
        const int o     = tid & 63;
        const float* mrow = meta + (size_t)(bn0 + bnode) * M_DIM;
        const float* brow = blw + o * M_DIM;
        float s = blb[o];
        #pragma unroll
        for (int m = 0; m < M_DIM; ++m) s += mrow[m] * brow[m];
        bias_s[bnode][o] = s;
    }

    // meta B-fragment (N cols = nodes; cols 8..15 duplicate, discarded on write)
    bf16x8 metaF;
    {
        const float* mp = meta + (size_t)(bn0 + (l16 & (NT - 1))) * M_DIM + g * 8;
        metaF = cvt8(*reinterpret_cast<const float4*>(mp),
                     *reinterpret_cast<const float4*>(mp + 4));
    }

    const f32x4 ZV = {0.f, 0.f, 0.f, 0.f};
    f32x4 acc[2][4];                             // [t-tile local][o-quarter]
    #pragma unroll
    for (int t = 0; t < 2; ++t)
        #pragma unroll
        for (int o = 0; o < 4; ++o) acc[t][o] = ZV;

    // hyper phase: wave owns o row (obase+wave); 6 tiles = 2 cc-halves x 3 k.
    // D lane(l16,g): col=node=l16 (valid l16<NT), rows cc = ch*16 + g*4 + r.
    auto hyper_phase = [&](int c0, int obase, int buf) {
        const int orow = obase + wave;
        #pragma unroll
        for (int ch = 0; ch < 2; ++ch) {
            #pragma unroll
            for (int k = 0; k < 3; ++k) {
                const int p = orow * 192 + (c0 + ch * 16 + l16) * 3 + k;
                bf16x8 aF;
                if constexpr (USE_WS) {
                    aF = *reinterpret_cast<const bf16x8*>(wlwbf + (size_t)p * M_DIM + g * 8);
                } else {
                    const float* wp = wlw + (size_t)p * M_DIM + g * 8;
                    aF = cvt8(*reinterpret_cast<const float4*>(wp),
                              *reinterpret_cast<const float4*>(wp + 4));
                }
                // fold w_lin_b into C operand: C[r] = wlb[p(cc=ch*16+g*4+r)]
                const int pb = orow * 192 + k;
                const int cb = c0 + ch * 16 + g * 4;
                f32x4 Cf;
                Cf[0] = wlb[pb + (cb + 0) * 3];
                Cf[1] = wlb[pb + (cb + 1) * 3];
                Cf[2] = wlb[pb + (cb + 2) * 3];
                Cf[3] = wlb[pb + (cb + 3) * 3];
                const f32x4 d = __builtin_amdgcn_mfma_f32_16x16x32_bf16(aF, metaF, Cf, 0, 0, 0);
                if (l16 < NT) {
                    const int off = buf + l16 * NODESTR + wave * OSTR + k * 32 + ch * 16 + g * 4;
                    *reinterpret_cast<short4*>(&wsh[off]) =
                        make_short4(f2bf(d[0]), f2bf(d[1]), f2bf(d[2]), f2bf(d[3]));
                }
            }
        }
    };

    const float* xb = x + (size_t)(bn0 + node) * (64 * C_IN);

    // prologue: fill buffer 0 with phase 0 (c0=0, oq=0)
    hyper_phase(0, 0, 0);
    __syncthreads();

    #pragma unroll 1
    for (int cchunk = 0; cchunk < 2; ++cchunk) {
        const int c0 = cchunk * 32;
        #pragma unroll
        for (int oq = 0; oq < 4; ++oq) {
            const int buf  = (oq & 1) * HALF;          // phase parity == oq parity
            const int bufn = ((oq + 1) & 1) * HALF;

            // hyper for next phase (skip after last)
            if (cchunk == 0 || oq < 3) {
                const int c0n = (oq == 3) ? c0 + 32 : c0;
                const int obn = ((oq + 1) & 3) * 16;
                hyper_phase(c0n, obn, bufn);
            }

            // conv on current phase: B-frags once, 2 t-tiles x 3 k full-K MFMAs
            const int bbase = buf + node * NODESTR + l16 * OSTR + g * 8;
            const bf16x8 B0 = *reinterpret_cast<const bf16x8*>(&wsh[bbase]);
            const bf16x8 B1 = *reinterpret_cast<const bf16x8*>(&wsh[bbase + 32]);
            const bf16x8 B2 = *reinterpret_cast<const bf16x8*>(&wsh[bbase + 64]);
            #pragma unroll
            for (int ttl = 0; ttl < 2; ++ttl) {
                const int t0 = (thalf * 2 + ttl) * 16;
                #pragma unroll
                for (int k = 0; k < 3; ++k) {
                    int row = t0 + l16 + k;
                    row = row < 63 ? row : 63;         // rows t>=62 are discarded
                    const float* xp = xb + row * C_IN + c0 + g * 8;
                    const bf16x8 A = cvt8(*reinterpret_cast<const float4*>(xp),
                                          *reinterpret_cast<const float4*>(xp + 4));
                    const bf16x8 Bk = (k == 0) ? B0 : (k == 1) ? B1 : B2;
                    acc[ttl][oq] = __builtin_amdgcn_mfma_f32_16x16x32_bf16(A, Bk, acc[ttl][oq], 0, 0, 0);
                }
            }
            __syncthreads();
        }
    }

    // ---------------- epilogue: add bias, store f32 ----------------
    float* ob = out + (size_t)(bn0 + node) * (S_OUT * C_OUT);
    #pragma unroll
    for (int ttl = 0; ttl < 2; ++ttl) {
        #pragma unroll
        for (int ot = 0; ot < 4; ++ot) {
            const int o  = ot * 16 + l16;
            const float bv = bias_s[node][o];
            #pragma unroll
            for (int r = 0; r < 4; ++r) {
                const int t = thalf * 32 + ttl * 16 + g * 4 + r;
                if (t < S_OUT) ob[t * C_OUT + o] = acc[ttl][ot][r] + bv;
            }
        }
    }
}

extern "C" void kernel_launch(void* const* d_in, const int* in_sizes, int n_in,
                              void* d_out, int out_size, void* d_ws, size_t ws_size,
                              hipStream_t stream) {
    const float* meta = (const float*)d_in[0];
    const float* x    = (const float*)d_in[1];
    const float* wlw  = (const float*)d_in[2];
    const float* wlb  = (const float*)d_in[3];
    const float* blw  = (const float*)d_in[4];
    const float* blb  = (const float*)d_in[5];
    float* out = (float*)d_out;
    (void)in_sizes; (void)n_in; (void)out_size;

    const size_t wlw_bytes = (size_t)WLW_ROWS * M_DIM * sizeof(short);  // 786432
    short* wlwbf = (short*)d_ws;

    if (ws_size >= wlw_bytes) {
        wlw_to_bf16<<<dim3(WLW_ROWS * M_DIM / (256 * 8)), dim3(256), 0, stream>>>(wlw, wlwbf);
        metaconv_fused<1><<<dim3(BN_TOT / NT), dim3(NTHREADS), 0, stream>>>(
            meta, x, wlw, wlwbf, wlb, blw, blb, out);
    } else {
        metaconv_fused<0><<<dim3(BN_TOT / NT), dim3(NTHREADS), 0, stream>>>(
            meta, x, wlw, wlwbf, wlb, blw, blb, out);
    }
}